// Round 1
// baseline (1396.815 us; speedup 1.0000x reference)
//
#include <hip/hip_runtime.h>
#include <cstddef>

#define HD 256
#define NHEAD 8
#define DHEAD 32
#define CAP 64

__global__ __launch_bounds__(256) void zero32_k(int* __restrict__ p, int n) {
    int i = blockIdx.x * 256 + threadIdx.x;
    if (i < n) p[i] = 0;
}

__global__ __launch_bounds__(256) void bucket_fill_k(const int* __restrict__ src,
                                                     const int* __restrict__ dst,
                                                     int* __restrict__ cnt,
                                                     int* __restrict__ bkt, int E) {
    int e = blockIdx.x * 256 + threadIdx.x;
    if (e >= E) return;
    int t = dst[e];
    int pos = atomicAdd(&cnt[t], 1);
    if (pos < CAP) bkt[(size_t)t * CAP + pos] = src[e];
}

// C[M,256] = A[M,K] @ B[K,256]  (f32, K % 8 == 0)
__global__ __launch_bounds__(256) void gemm256_k(const float* __restrict__ A,
                                                 const float* __restrict__ B,
                                                 float* __restrict__ C, int M, int K) {
    __shared__ float As[8][132];   // [k][m], padded: row stride 132 f = 528 B (16B aligned)
    __shared__ float Bs[8][132];   // [k][n]
    const int tid = threadIdx.x;
    const int bm = blockIdx.y * 128;
    const int bn = blockIdx.x * 128;
    const int ty = tid >> 4, tx = tid & 15;

    const int arow = tid >> 1, akc = (tid & 1) * 4;
    int grow = bm + arow; if (grow > M - 1) grow = M - 1;
    const float* aptr = A + (size_t)grow * K + akc;

    const int bkr = tid >> 5, bcol = (tid & 31) * 4;
    const float* bptr = B + (size_t)bkr * HD + bn + bcol;

    float acc[8][8];
#pragma unroll
    for (int i = 0; i < 8; i++)
#pragma unroll
        for (int j = 0; j < 8; j++) acc[i][j] = 0.f;

    for (int k0 = 0; k0 < K; k0 += 8) {
        float4 av = *(const float4*)aptr; aptr += 8;
        float4 bv = *(const float4*)bptr; bptr += 8 * HD;
        __syncthreads();
        As[akc + 0][arow] = av.x;
        As[akc + 1][arow] = av.y;
        As[akc + 2][arow] = av.z;
        As[akc + 3][arow] = av.w;
        *(float4*)&Bs[bkr][bcol] = bv;
        __syncthreads();
#pragma unroll
        for (int kk = 0; kk < 8; kk++) {
            float af[8], bf[8];
            *(float4*)(af)     = *(const float4*)&As[kk][ty * 8];
            *(float4*)(af + 4) = *(const float4*)&As[kk][ty * 8 + 4];
            *(float4*)(bf)     = *(const float4*)&Bs[kk][tx * 8];
            *(float4*)(bf + 4) = *(const float4*)&Bs[kk][tx * 8 + 4];
#pragma unroll
            for (int i = 0; i < 8; i++)
#pragma unroll
                for (int j = 0; j < 8; j++)
                    acc[i][j] = fmaf(af[i], bf[j], acc[i][j]);
        }
    }
#pragma unroll
    for (int i = 0; i < 8; i++) {
        int r = bm + ty * 8 + i;
        if (r < M) {
            float* cp = C + (size_t)r * HD + bn + tx * 8;
            *(float4*)cp       = make_float4(acc[i][0], acc[i][1], acc[i][2], acc[i][3]);
            *(float4*)(cp + 4) = make_float4(acc[i][4], acc[i][5], acc[i][6], acc[i][7]);
        }
    }
}

// per (node,head): a_s = dot(h[n,h,:], a_src[h,:]), a_d likewise
__global__ __launch_bounds__(256) void attscore_k(const float* __restrict__ h,
                                                  const float* __restrict__ a_src,
                                                  const float* __restrict__ a_dst,
                                                  float* __restrict__ out_s,
                                                  float* __restrict__ out_d, int n) {
    int idx = blockIdx.x * 256 + threadIdx.x;
    if (idx >= n * NHEAD) return;
    int head = idx & 7;
    const float* hp = h + (size_t)(idx >> 3) * HD + head * DHEAD;
    const float* ap = a_src + head * DHEAD;
    const float* dp = a_dst + head * DHEAD;
    float s = 0.f, d = 0.f;
#pragma unroll
    for (int j = 0; j < DHEAD; j += 4) {
        float4 hv = *(const float4*)(hp + j);
        float4 av = *(const float4*)(ap + j);
        float4 dv = *(const float4*)(dp + j);
        s += hv.x * av.x + hv.y * av.y + hv.z * av.z + hv.w * av.w;
        d += hv.x * dv.x + hv.y * dv.y + hv.z * dv.z + hv.w * dv.w;
    }
    out_s[idx] = s;
    out_d[idx] = d;
}

__device__ __forceinline__ float leaky02(float x) { return x > 0.f ? x : 0.2f * x; }

// one wave per dst node; online softmax over {self-loop} ∪ incoming edges.
// lane handles features [lane*4, lane*4+4); head = lane>>3.
__global__ __launch_bounds__(256) void agg_k(const float* __restrict__ h,
                                             const float* __restrict__ a_s,
                                             const float* __restrict__ a_d,
                                             const int* __restrict__ cnt,
                                             const int* __restrict__ bkt,
                                             const float* __restrict__ bias,
                                             float* __restrict__ out, int n) {
    int wid = (blockIdx.x * 256 + threadIdx.x) >> 6;
    if (wid >= n) return;
    int lane = threadIdx.x & 63;
    int head = lane >> 3;
    const float4* h4 = (const float4*)h;

    float adt = a_d[wid * NHEAD + head];
    // self loop first
    float m = leaky02(a_s[wid * NHEAD + head] + adt);
    float den = 1.f;
    float4 hv = h4[(size_t)wid * 64 + lane];
    float ax = hv.x, ay = hv.y, az = hv.z, aw = hv.w;

    int k = cnt[wid]; if (k > CAP) k = CAP;
    const int* bp = bkt + (size_t)wid * CAP;
    for (int i = 0; i < k; i++) {
        int s = bp[i];
        float e = leaky02(a_s[s * NHEAD + head] + adt);
        float nm = fmaxf(m, e);
        float corr = __expf(m - nm);
        float p = __expf(e - nm);
        float4 v = h4[(size_t)s * 64 + lane];
        den = den * corr + p;
        ax = ax * corr + p * v.x;
        ay = ay * corr + p * v.y;
        az = az * corr + p * v.z;
        aw = aw * corr + p * v.w;
        m = nm;
    }
    float inv = 1.f / den;   // den >= 1, ref's +1e-16 negligible
    float4 bv = *(const float4*)(bias + lane * 4);
    float ox = fmaf(ax, inv, bv.x);
    float oy = fmaf(ay, inv, bv.y);
    float oz = fmaf(az, inv, bv.z);
    float ow = fmaf(aw, inv, bv.w);
    // ELU (all four GAT layer outputs pass through elu)
    ox = ox > 0.f ? ox : expm1f(ox);
    oy = oy > 0.f ? oy : expm1f(oy);
    oz = oz > 0.f ? oz : expm1f(oz);
    ow = ow > 0.f ? ow : expm1f(ow);
    ((float4*)out)[(size_t)wid * 64 + lane] = make_float4(ox, oy, oz, ow);
}

// fused: channel scores -> softmax weights -> weighted concat -> fc1+elu -> fc2 -> log_softmax
__global__ __launch_bounds__(256) void head_k(const float* __restrict__ cb,
                                              const float* __restrict__ sb,
                                              const float* __restrict__ attc_w,
                                              const float* __restrict__ attc_b,
                                              const float* __restrict__ atts_w,
                                              const float* __restrict__ atts_b,
                                              const float* __restrict__ fc1_w,
                                              const float* __restrict__ fc1_b,
                                              const float* __restrict__ fc2_w,
                                              const float* __restrict__ fc2_b,
                                              float* __restrict__ out, int n) {
    int wid = (blockIdx.x * 256 + threadIdx.x) >> 6;
    if (wid >= n) return;
    int lane = threadIdx.x & 63;
    const float* c = cb + (size_t)wid * HD;
    const float* s = sb + (size_t)wid * HD;

    float4 cv = *(const float4*)(c + lane * 4);
    float4 wc = *(const float4*)(attc_w + lane * 4);
    float4 sv = *(const float4*)(s + lane * 4);
    float4 ws = *(const float4*)(atts_w + lane * 4);
    float pc = cv.x * wc.x + cv.y * wc.y + cv.z * wc.z + cv.w * wc.w;
    float ps = sv.x * ws.x + sv.y * ws.y + sv.z * ws.z + sv.w * ws.w;
#pragma unroll
    for (int o = 32; o; o >>= 1) { pc += __shfl_xor(pc, o); ps += __shfl_xor(ps, o); }
    float csc = 1.f / (1.f + __expf(-(pc + attc_b[0])));
    float ssc = 1.f / (1.f + __expf(-(ps + atts_b[0])));
    float mx0 = fmaxf(csc, ssc);
    float e0 = __expf(csc - mx0), e1 = __expf(ssc - mx0);
    float w0 = e0 / (e0 + e1), w1 = e1 / (e0 + e1);

    int col = lane & 31, half = lane >> 5;
    const float* xb = half ? s : c;
    float wsc = half ? w1 : w0;
    const float* fw = fc1_w + (size_t)half * HD * 32 + col;
    float acc = 0.f;
#pragma unroll 4
    for (int kk = 0; kk < HD; kk++) acc = fmaf(xb[kk], fw[kk * 32], acc);
    acc *= wsc;
    float y = acc + __shfl_xor(acc, 32) + fc1_b[col];
    y = y > 0.f ? y : expm1f(y);
    float v = y * fc2_w[col * 2 + half];
#pragma unroll
    for (int o = 16; o; o >>= 1) v += __shfl_xor(v, o);
    float z0 = __shfl(v, 0), z1 = __shfl(v, 32);
    if (lane == 0) {
        float zm = fmaxf(z0, z1);
        float lse = zm + log1pf(__expf(fminf(z0, z1) - zm));
        out[(size_t)wid * 2]     = z0 - lse;
        out[(size_t)wid * 2 + 1] = z1 - lse;
    }
}

extern "C" void kernel_launch(void* const* d_in, const int* in_sizes, int n_in,
                              void* d_out, int out_size, void* d_ws, size_t ws_size,
                              hipStream_t stream) {
    (void)n_in; (void)out_size; (void)ws_size;
    const float* content_x = (const float*)d_in[0];
    const float* social_x  = (const float*)d_in[1];
    const int*   cei = (const int*)d_in[2];
    const int*   sei = (const int*)d_in[3];
    const float* Wc0  = (const float*)d_in[4];
    const float* ac0s = (const float*)d_in[5];
    const float* ac0d = (const float*)d_in[6];
    const float* bc0  = (const float*)d_in[7];
    const float* Wc1  = (const float*)d_in[8];
    const float* ac1s = (const float*)d_in[9];
    const float* ac1d = (const float*)d_in[10];
    const float* bc1  = (const float*)d_in[11];
    const float* Ws0  = (const float*)d_in[12];
    const float* as0s = (const float*)d_in[13];
    const float* as0d = (const float*)d_in[14];
    const float* bs0  = (const float*)d_in[15];
    const float* Ws1  = (const float*)d_in[16];
    const float* as1s = (const float*)d_in[17];
    const float* as1d = (const float*)d_in[18];
    const float* bs1  = (const float*)d_in[19];
    const float* attc_w = (const float*)d_in[20];
    const float* attc_b = (const float*)d_in[21];
    const float* atts_w = (const float*)d_in[22];
    const float* atts_b = (const float*)d_in[23];
    const float* fc1_w  = (const float*)d_in[24];
    const float* fc1_b  = (const float*)d_in[25];
    const float* fc2_w  = (const float*)d_in[26];
    const float* fc2_b  = (const float*)d_in[27];

    const int E  = in_sizes[2] / 2;        // 400000
    const int CD = in_sizes[4] / HD;       // 768
    const int SD = in_sizes[12] / HD;      // 128
    const int n  = in_sizes[0] / CD;       // 50000

    char* p = (char*)d_ws;
    auto carve = [&](size_t bytes) { char* q = p; p += (bytes + 255) & ~(size_t)255; return q; };
    float* hbuf = (float*)carve((size_t)n * HD * 4);
    float* cbuf = (float*)carve((size_t)n * HD * 4);
    float* sbuf = (float*)carve((size_t)n * HD * 4);
    float* asb  = (float*)carve((size_t)n * NHEAD * 4);
    float* adb  = (float*)carve((size_t)n * NHEAD * 4);
    int* cnt_c  = (int*)carve((size_t)n * 4);
    int* cnt_s  = (int*)carve((size_t)n * 4);
    int* bkt_c  = (int*)carve((size_t)n * CAP * 4);
    int* bkt_s  = (int*)carve((size_t)n * CAP * 4);

    zero32_k<<<dim3((n + 255) / 256), 256, 0, stream>>>(cnt_c, n);
    zero32_k<<<dim3((n + 255) / 256), 256, 0, stream>>>(cnt_s, n);
    bucket_fill_k<<<dim3((E + 255) / 256), 256, 0, stream>>>(cei, cei + E, cnt_c, bkt_c, E);
    bucket_fill_k<<<dim3((E + 255) / 256), 256, 0, stream>>>(sei, sei + E, cnt_s, bkt_s, E);

    dim3 gg(2, (n + 127) / 128);
    dim3 nb8((n * NHEAD + 255) / 256);
    dim3 nwave((n + 3) / 4);

    // content layer 0
    gemm256_k<<<gg, 256, 0, stream>>>(content_x, Wc0, hbuf, n, CD);
    attscore_k<<<nb8, 256, 0, stream>>>(hbuf, ac0s, ac0d, asb, adb, n);
    agg_k<<<nwave, 256, 0, stream>>>(hbuf, asb, adb, cnt_c, bkt_c, bc0, cbuf, n);
    // content layer 1
    gemm256_k<<<gg, 256, 0, stream>>>(cbuf, Wc1, hbuf, n, HD);
    attscore_k<<<nb8, 256, 0, stream>>>(hbuf, ac1s, ac1d, asb, adb, n);
    agg_k<<<nwave, 256, 0, stream>>>(hbuf, asb, adb, cnt_c, bkt_c, bc1, cbuf, n);
    // social layer 0
    gemm256_k<<<gg, 256, 0, stream>>>(social_x, Ws0, hbuf, n, SD);
    attscore_k<<<nb8, 256, 0, stream>>>(hbuf, as0s, as0d, asb, adb, n);
    agg_k<<<nwave, 256, 0, stream>>>(hbuf, asb, adb, cnt_s, bkt_s, bs0, sbuf, n);
    // social layer 1
    gemm256_k<<<gg, 256, 0, stream>>>(sbuf, Ws1, hbuf, n, HD);
    attscore_k<<<nb8, 256, 0, stream>>>(hbuf, as1s, as1d, asb, adb, n);
    agg_k<<<nwave, 256, 0, stream>>>(hbuf, asb, adb, cnt_s, bkt_s, bs1, sbuf, n);

    head_k<<<nwave, 256, 0, stream>>>(cbuf, sbuf, attc_w, attc_b, atts_w, atts_b,
                                      fc1_w, fc1_b, fc2_w, fc2_b, (float*)d_out, n);
}

// Round 3
// 1151.706 us; speedup vs baseline: 1.2128x; 1.2128x over previous
//
#include <hip/hip_runtime.h>
#include <cstddef>
#include <cstdint>

#define HD 256
#define NHEAD 8
#define CAP 64

typedef __attribute__((ext_vector_type(8))) short bf16x8;
typedef __attribute__((ext_vector_type(4))) float f32x4;

__device__ __forceinline__ unsigned short f2bf(float f) {
    unsigned u = __float_as_uint(f);
    u += 0x7fffu + ((u >> 16) & 1u);
    return (unsigned short)(u >> 16);
}
__device__ __forceinline__ float bf2f(unsigned short h) {
    return __uint_as_float(((unsigned)h) << 16);
}

__device__ __forceinline__ void gload16(const unsigned short* g, unsigned short* l) {
    __builtin_amdgcn_global_load_lds((const __attribute__((address_space(1))) unsigned int*)g,
                                     (__attribute__((address_space(3))) unsigned int*)l,
                                     16, 0, 0);
}

__global__ __launch_bounds__(256) void zero32_k(int* __restrict__ p, int n) {
    int i = blockIdx.x * 256 + threadIdx.x;
    if (i < n) p[i] = 0;
}

__global__ __launch_bounds__(256) void bucket_fill_k(const int* __restrict__ src,
                                                     const int* __restrict__ dst,
                                                     int* __restrict__ cnt,
                                                     int* __restrict__ bkt, int E) {
    int e = blockIdx.x * 256 + threadIdx.x;
    if (e >= E) return;
    int t = dst[e];
    int pos = atomicAdd(&cnt[t], 1);
    if (pos < CAP) bkt[(size_t)t * CAP + pos] = src[e];
}

// fp32 -> bf16 hi + bf16 lo (residual), vectorized
__global__ __launch_bounds__(256) void split_k(const float* __restrict__ x,
                                               unsigned short* __restrict__ hi,
                                               unsigned short* __restrict__ lo,
                                               int n4) {
    int i = blockIdx.x * 256 + threadIdx.x;
    int stride = gridDim.x * 256;
    for (; i < n4; i += stride) {
        float4 v = ((const float4*)x)[i];
        ushort4 h, l;
        h.x = f2bf(v.x); l.x = f2bf(v.x - bf2f(h.x));
        h.y = f2bf(v.y); l.y = f2bf(v.y - bf2f(h.y));
        h.z = f2bf(v.z); l.z = f2bf(v.z - bf2f(h.z));
        h.w = f2bf(v.w); l.w = f2bf(v.w - bf2f(h.w));
        ((ushort4*)hi)[i] = h;
        ((ushort4*)lo)[i] = l;
    }
}

// W [K][256] fp32 -> Wt hi/lo [256][K] bf16 (transpose + split; tiny)
__global__ __launch_bounds__(256) void wsplit_k(const float* __restrict__ W,
                                                unsigned short* __restrict__ hi,
                                                unsigned short* __restrict__ lo, int K) {
    int idx = blockIdx.x * 256 + threadIdx.x;
    if (idx >= K * HD) return;
    int n = idx / K, k = idx - n * K;
    float v = W[(size_t)k * HD + n];
    unsigned short h = f2bf(v);
    hi[idx] = h;
    lo[idx] = f2bf(v - bf2f(h));
}

// C[M,256] = A[M,K] @ B[K,256], split-bf16 MFMA (Ah*Bh + Ah*Bl + Al*Bh), fp32 out.
// A given as hi/lo [M][K] bf16; B given as TRANSPOSED hi/lo [256][K] bf16.
// 128x128 tile, BK=32, 4 waves of 64x64. global_load_lds staging with
// read-side XOR swizzle (slot ^= (row>>1)&3) pre-applied to the global source.
__global__ __launch_bounds__(256, 2) void gemm_mfma_k(
    const unsigned short* __restrict__ Ahi, const unsigned short* __restrict__ Alo,
    const unsigned short* __restrict__ Bhi, const unsigned short* __restrict__ Blo,
    float* __restrict__ C, int M, int K) {
    __shared__ unsigned short smem[4 * 128 * 32];   // Ahi | Alo | Bhi | Blo, 8KB each
    const int tid = threadIdx.x;
    const int lane = tid & 63;
    const int wv = tid >> 6;
    const int Rw = (wv >> 1) * 64;
    const int Cw = (wv & 1) * 64;
    const int bm = blockIdx.y * 128;
    const int bn = blockIdx.x * 128;

    // staging: issue covers 64 rows; thread -> (row = issue*64 + tid/4, slot = tid&3)
    const int sr0 = tid >> 2;
    const int p = tid & 3;
    const int g0 = p ^ ((sr0 >> 1) & 3);            // inverse-swizzled source slot
    const int g1 = p ^ (((sr0 + 64) >> 1) & 3);
    int ar0 = bm + sr0;      if (ar0 >= M) ar0 = M - 1;
    int ar1 = bm + sr0 + 64; if (ar1 >= M) ar1 = M - 1;
    const int bc0 = bn + sr0;
    const int bc1 = bn + sr0 + 64;
    const size_t aoff0 = (size_t)ar0 * K + g0 * 8;
    const size_t aoff1 = (size_t)ar1 * K + g1 * 8;
    const size_t boff0 = (size_t)bc0 * K + g0 * 8;
    const size_t boff1 = (size_t)bc1 * K + g1 * 8;

    unsigned short* sAh = smem;
    unsigned short* sAl = smem + 4096;
    unsigned short* sBh = smem + 8192;
    unsigned short* sBl = smem + 12288;
    const int ldsb = wv * 512;                      // wave-uniform base (ushorts)

    f32x4 acc[4][4];
#pragma unroll
    for (int m = 0; m < 4; m++)
#pragma unroll
        for (int n = 0; n < 4; n++) acc[m][n] = (f32x4){0.f, 0.f, 0.f, 0.f};

    const int r16 = lane & 15, gq = lane >> 4;
    const int rsw = gq ^ ((r16 >> 1) & 3);          // swizzled read slot

    for (int k0 = 0; k0 < K; k0 += 32) {
        __syncthreads();
        gload16(Ahi + aoff0 + k0, sAh + ldsb);
        gload16(Ahi + aoff1 + k0, sAh + 2048 + ldsb);
        gload16(Alo + aoff0 + k0, sAl + ldsb);
        gload16(Alo + aoff1 + k0, sAl + 2048 + ldsb);
        gload16(Bhi + boff0 + k0, sBh + ldsb);
        gload16(Bhi + boff1 + k0, sBh + 2048 + ldsb);
        gload16(Blo + boff0 + k0, sBl + ldsb);
        gload16(Blo + boff1 + k0, sBl + 2048 + ldsb);
        __syncthreads();

        bf16x8 ah[4], al[4], bh[4], bl[4];
#pragma unroll
        for (int m = 0; m < 4; m++) {
            int off = (Rw + m * 16 + r16) * 32 + rsw * 8;
            ah[m] = *(const bf16x8*)(sAh + off);
            al[m] = *(const bf16x8*)(sAl + off);
        }
#pragma unroll
        for (int n = 0; n < 4; n++) {
            int off = (Cw + n * 16 + r16) * 32 + rsw * 8;
            bh[n] = *(const bf16x8*)(sBh + off);
            bl[n] = *(const bf16x8*)(sBl + off);
        }
#pragma unroll
        for (int m = 0; m < 4; m++)
#pragma unroll
            for (int n = 0; n < 4; n++) {
                acc[m][n] = __builtin_amdgcn_mfma_f32_16x16x32_bf16(ah[m], bh[n], acc[m][n], 0, 0, 0);
                acc[m][n] = __builtin_amdgcn_mfma_f32_16x16x32_bf16(ah[m], bl[n], acc[m][n], 0, 0, 0);
                acc[m][n] = __builtin_amdgcn_mfma_f32_16x16x32_bf16(al[m], bh[n], acc[m][n], 0, 0, 0);
            }
    }

#pragma unroll
    for (int m = 0; m < 4; m++) {
        int rbase = bm + Rw + m * 16 + ((lane >> 4) << 2);
#pragma unroll
        for (int n = 0; n < 4; n++) {
            int col = bn + Cw + n * 16 + r16;
            float* cp = C + (size_t)rbase * HD + col;
            f32x4 v = acc[m][n];
#pragma unroll
            for (int r = 0; r < 4; r++)
                if (rbase + r < M) cp[(size_t)r * HD] = v[r];
        }
    }
}

// per (node,head): a_s = dot(h[n,h,:], a_src[h,:]), a_d likewise
__global__ __launch_bounds__(256) void attscore_k(const float* __restrict__ h,
                                                  const float* __restrict__ a_src,
                                                  const float* __restrict__ a_dst,
                                                  float* __restrict__ out_s,
                                                  float* __restrict__ out_d, int n) {
    int idx = blockIdx.x * 256 + threadIdx.x;
    if (idx >= n * NHEAD) return;
    int head = idx & 7;
    const float* hp = h + (size_t)(idx >> 3) * HD + head * 32;
    const float* ap = a_src + head * 32;
    const float* dp = a_dst + head * 32;
    float s = 0.f, d = 0.f;
#pragma unroll
    for (int j = 0; j < 32; j += 4) {
        float4 hv = *(const float4*)(hp + j);
        float4 av = *(const float4*)(ap + j);
        float4 dv = *(const float4*)(dp + j);
        s += hv.x * av.x + hv.y * av.y + hv.z * av.z + hv.w * av.w;
        d += hv.x * dv.x + hv.y * dv.y + hv.z * dv.z + hv.w * dv.w;
    }
    out_s[idx] = s;
    out_d[idx] = d;
}

__device__ __forceinline__ float leaky02(float x) { return x > 0.f ? x : 0.2f * x; }

// one wave per dst node; online softmax over {self-loop} ∪ incoming edges.
// optionally emits bf16 hi/lo of the ELU output (next layer's GEMM input).
__global__ __launch_bounds__(256) void agg_k(const float* __restrict__ h,
                                             const float* __restrict__ a_s,
                                             const float* __restrict__ a_d,
                                             const int* __restrict__ cnt,
                                             const int* __restrict__ bkt,
                                             const float* __restrict__ bias,
                                             float* __restrict__ out,
                                             unsigned short* __restrict__ ohi,
                                             unsigned short* __restrict__ olo, int n) {
    int wid = (blockIdx.x * 256 + threadIdx.x) >> 6;
    if (wid >= n) return;
    int lane = threadIdx.x & 63;
    int head = lane >> 3;
    const float4* h4 = (const float4*)h;

    float adt = a_d[wid * NHEAD + head];
    float m = leaky02(a_s[wid * NHEAD + head] + adt);
    float den = 1.f;
    float4 hv = h4[(size_t)wid * 64 + lane];
    float ax = hv.x, ay = hv.y, az = hv.z, aw = hv.w;

    int k = cnt[wid]; if (k > CAP) k = CAP;
    const int* bp = bkt + (size_t)wid * CAP;
    for (int i = 0; i < k; i++) {
        int s = bp[i];
        float e = leaky02(a_s[s * NHEAD + head] + adt);
        float nm = fmaxf(m, e);
        float corr = __expf(m - nm);
        float pp = __expf(e - nm);
        float4 v = h4[(size_t)s * 64 + lane];
        den = den * corr + pp;
        ax = ax * corr + pp * v.x;
        ay = ay * corr + pp * v.y;
        az = az * corr + pp * v.z;
        aw = aw * corr + pp * v.w;
        m = nm;
    }
    float inv = 1.f / den;
    float4 bv = *(const float4*)(bias + lane * 4);
    float ox = fmaf(ax, inv, bv.x);
    float oy = fmaf(ay, inv, bv.y);
    float oz = fmaf(az, inv, bv.z);
    float ow = fmaf(aw, inv, bv.w);
    ox = ox > 0.f ? ox : expm1f(ox);
    oy = oy > 0.f ? oy : expm1f(oy);
    oz = oz > 0.f ? oz : expm1f(oz);
    ow = ow > 0.f ? ow : expm1f(ow);
    ((float4*)out)[(size_t)wid * 64 + lane] = make_float4(ox, oy, oz, ow);
    if (ohi) {
        ushort4 h4o, l4o;
        h4o.x = f2bf(ox); l4o.x = f2bf(ox - bf2f(h4o.x));
        h4o.y = f2bf(oy); l4o.y = f2bf(oy - bf2f(h4o.y));
        h4o.z = f2bf(oz); l4o.z = f2bf(oz - bf2f(h4o.z));
        h4o.w = f2bf(ow); l4o.w = f2bf(ow - bf2f(h4o.w));
        ((ushort4*)ohi)[(size_t)wid * 64 + lane] = h4o;
        ((ushort4*)olo)[(size_t)wid * 64 + lane] = l4o;
    }
}

// fused: channel scores -> softmax weights -> weighted concat -> fc1+elu -> fc2 -> log_softmax
__global__ __launch_bounds__(256) void head_k(const float* __restrict__ cb,
                                              const float* __restrict__ sb,
                                              const float* __restrict__ attc_w,
                                              const float* __restrict__ attc_b,
                                              const float* __restrict__ atts_w,
                                              const float* __restrict__ atts_b,
                                              const float* __restrict__ fc1_w,
                                              const float* __restrict__ fc1_b,
                                              const float* __restrict__ fc2_w,
                                              const float* __restrict__ fc2_b,
                                              float* __restrict__ out, int n) {
    int wid = (blockIdx.x * 256 + threadIdx.x) >> 6;
    if (wid >= n) return;
    int lane = threadIdx.x & 63;
    const float* c = cb + (size_t)wid * HD;
    const float* s = sb + (size_t)wid * HD;

    float4 cv = *(const float4*)(c + lane * 4);
    float4 wc = *(const float4*)(attc_w + lane * 4);
    float4 sv = *(const float4*)(s + lane * 4);
    float4 ws = *(const float4*)(atts_w + lane * 4);
    float pc = cv.x * wc.x + cv.y * wc.y + cv.z * wc.z + cv.w * wc.w;
    float ps = sv.x * ws.x + sv.y * ws.y + sv.z * ws.z + sv.w * ws.w;
#pragma unroll
    for (int o = 32; o; o >>= 1) { pc += __shfl_xor(pc, o); ps += __shfl_xor(ps, o); }
    float csc = 1.f / (1.f + __expf(-(pc + attc_b[0])));
    float ssc = 1.f / (1.f + __expf(-(ps + atts_b[0])));
    float mx0 = fmaxf(csc, ssc);
    float e0 = __expf(csc - mx0), e1 = __expf(ssc - mx0);
    float w0 = e0 / (e0 + e1), w1 = e1 / (e0 + e1);

    int col = lane & 31, half = lane >> 5;
    const float* xb = half ? s : c;
    float wsc = half ? w1 : w0;
    const float* fw = fc1_w + (size_t)half * HD * 32 + col;
    float acc = 0.f;
#pragma unroll 4
    for (int kk = 0; kk < HD; kk++) acc = fmaf(xb[kk], fw[kk * 32], acc);
    acc *= wsc;
    float y = acc + __shfl_xor(acc, 32) + fc1_b[col];
    y = y > 0.f ? y : expm1f(y);
    float v = y * fc2_w[col * 2 + half];
#pragma unroll
    for (int o = 16; o; o >>= 1) v += __shfl_xor(v, o);
    float z0 = __shfl(v, 0), z1 = __shfl(v, 32);
    if (lane == 0) {
        float zm = fmaxf(z0, z1);
        float lse = zm + log1pf(__expf(fminf(z0, z1) - zm));
        out[(size_t)wid * 2]     = z0 - lse;
        out[(size_t)wid * 2 + 1] = z1 - lse;
    }
}

extern "C" void kernel_launch(void* const* d_in, const int* in_sizes, int n_in,
                              void* d_out, int out_size, void* d_ws, size_t ws_size,
                              hipStream_t stream) {
    (void)n_in; (void)out_size; (void)ws_size;
    const float* content_x = (const float*)d_in[0];
    const float* social_x  = (const float*)d_in[1];
    const int*   cei = (const int*)d_in[2];
    const int*   sei = (const int*)d_in[3];
    const float* Wc0  = (const float*)d_in[4];
    const float* ac0s = (const float*)d_in[5];
    const float* ac0d = (const float*)d_in[6];
    const float* bc0  = (const float*)d_in[7];
    const float* Wc1  = (const float*)d_in[8];
    const float* ac1s = (const float*)d_in[9];
    const float* ac1d = (const float*)d_in[10];
    const float* bc1  = (const float*)d_in[11];
    const float* Ws0  = (const float*)d_in[12];
    const float* as0s = (const float*)d_in[13];
    const float* as0d = (const float*)d_in[14];
    const float* bs0  = (const float*)d_in[15];
    const float* Ws1  = (const float*)d_in[16];
    const float* as1s = (const float*)d_in[17];
    const float* as1d = (const float*)d_in[18];
    const float* bs1  = (const float*)d_in[19];
    const float* attc_w = (const float*)d_in[20];
    const float* attc_b = (const float*)d_in[21];
    const float* atts_w = (const float*)d_in[22];
    const float* atts_b = (const float*)d_in[23];
    const float* fc1_w  = (const float*)d_in[24];
    const float* fc1_b  = (const float*)d_in[25];
    const float* fc2_w  = (const float*)d_in[26];
    const float* fc2_b  = (const float*)d_in[27];

    const int E  = in_sizes[2] / 2;        // 400000
    const int CD = in_sizes[4] / HD;       // 768
    const int SD = in_sizes[12] / HD;      // 128
    const int n  = in_sizes[0] / CD;       // 50000

    char* p = (char*)d_ws;
    auto carve = [&](size_t bytes) { char* q = p; p += (bytes + 255) & ~(size_t)255; return q; };
    float* hbuf = (float*)carve((size_t)n * HD * 4);
    float* cbuf = (float*)carve((size_t)n * HD * 4);
    float* sbuf = (float*)carve((size_t)n * HD * 4);
    unsigned short* Xhi = (unsigned short*)carve((size_t)n * CD * 2);
    unsigned short* Xlo = (unsigned short*)carve((size_t)n * CD * 2);
    float* asb  = (float*)carve((size_t)n * NHEAD * 4);
    float* adb  = (float*)carve((size_t)n * NHEAD * 4);
    int* cnt_c  = (int*)carve((size_t)n * 4);
    int* cnt_s  = (int*)carve((size_t)n * 4);
    int* bkt_c  = (int*)carve((size_t)n * CAP * 4);
    int* bkt_s  = (int*)carve((size_t)n * CAP * 4);
    unsigned short* Wc0h = (unsigned short*)carve((size_t)CD * HD * 2);
    unsigned short* Wc0l = (unsigned short*)carve((size_t)CD * HD * 2);
    unsigned short* Wc1h = (unsigned short*)carve((size_t)HD * HD * 2);
    unsigned short* Wc1l = (unsigned short*)carve((size_t)HD * HD * 2);
    unsigned short* Ws0h = (unsigned short*)carve((size_t)SD * HD * 2);
    unsigned short* Ws0l = (unsigned short*)carve((size_t)SD * HD * 2);
    unsigned short* Ws1h = (unsigned short*)carve((size_t)HD * HD * 2);
    unsigned short* Ws1l = (unsigned short*)carve((size_t)HD * HD * 2);

    dim3 b256(256);
    zero32_k<<<dim3((n + 255) / 256), b256, 0, stream>>>(cnt_c, n);
    zero32_k<<<dim3((n + 255) / 256), b256, 0, stream>>>(cnt_s, n);
    bucket_fill_k<<<dim3((E + 255) / 256), b256, 0, stream>>>(cei, cei + E, cnt_c, bkt_c, E);
    bucket_fill_k<<<dim3((E + 255) / 256), b256, 0, stream>>>(sei, sei + E, cnt_s, bkt_s, E);

    // weight transpose+split (tiny)
    wsplit_k<<<dim3((CD * HD + 255) / 256), b256, 0, stream>>>(Wc0, Wc0h, Wc0l, CD);
    wsplit_k<<<dim3((HD * HD + 255) / 256), b256, 0, stream>>>(Wc1, Wc1h, Wc1l, HD);
    wsplit_k<<<dim3((SD * HD + 255) / 256), b256, 0, stream>>>(Ws0, Ws0h, Ws0l, SD);
    wsplit_k<<<dim3((HD * HD + 255) / 256), b256, 0, stream>>>(Ws1, Ws1h, Ws1l, HD);

    dim3 gg(2, (n + 127) / 128);
    dim3 nb8((n * NHEAD + 255) / 256);
    dim3 nwave((n + 3) / 4);

    // content layer 0
    split_k<<<dim3(2048), b256, 0, stream>>>(content_x, Xhi, Xlo, n * CD / 4);
    gemm_mfma_k<<<gg, b256, 0, stream>>>(Xhi, Xlo, Wc0h, Wc0l, hbuf, n, CD);
    attscore_k<<<nb8, b256, 0, stream>>>(hbuf, ac0s, ac0d, asb, adb, n);
    agg_k<<<nwave, b256, 0, stream>>>(hbuf, asb, adb, cnt_c, bkt_c, bc0, cbuf, Xhi, Xlo, n);
    // content layer 1
    gemm_mfma_k<<<gg, b256, 0, stream>>>(Xhi, Xlo, Wc1h, Wc1l, hbuf, n, HD);
    attscore_k<<<nb8, b256, 0, stream>>>(hbuf, ac1s, ac1d, asb, adb, n);
    agg_k<<<nwave, b256, 0, stream>>>(hbuf, asb, adb, cnt_c, bkt_c, bc1, cbuf,
                                      (unsigned short*)nullptr, (unsigned short*)nullptr, n);
    // social layer 0
    split_k<<<dim3(2048), b256, 0, stream>>>(social_x, Xhi, Xlo, n * SD / 4);
    gemm_mfma_k<<<gg, b256, 0, stream>>>(Xhi, Xlo, Ws0h, Ws0l, hbuf, n, SD);
    attscore_k<<<nb8, b256, 0, stream>>>(hbuf, as0s, as0d, asb, adb, n);
    agg_k<<<nwave, b256, 0, stream>>>(hbuf, asb, adb, cnt_s, bkt_s, bs0, sbuf, Xhi, Xlo, n);
    // social layer 1
    gemm_mfma_k<<<gg, b256, 0, stream>>>(Xhi, Xlo, Ws1h, Ws1l, hbuf, n, HD);
    attscore_k<<<nb8, b256, 0, stream>>>(hbuf, as1s, as1d, asb, adb, n);
    agg_k<<<nwave, b256, 0, stream>>>(hbuf, asb, adb, cnt_s, bkt_s, bs1, sbuf,
                                      (unsigned short*)nullptr, (unsigned short*)nullptr, n);

    head_k<<<nwave, b256, 0, stream>>>(cbuf, sbuf, attc_w, attc_b, atts_w, atts_b,
                                       fc1_w, fc1_b, fc2_w, fc2_b, (float*)d_out, n);
}

// Round 4
// 1122.867 us; speedup vs baseline: 1.2440x; 1.0257x over previous
//
#include <hip/hip_runtime.h>
#include <cstddef>
#include <cstdint>

#define HD 256
#define NHEAD 8
#define CAP 64

typedef __attribute__((ext_vector_type(8))) short bf16x8;
typedef __attribute__((ext_vector_type(4))) float f32x4;

__device__ __forceinline__ unsigned short f2bf(float f) {
    unsigned u = __float_as_uint(f);
    u += 0x7fffu + ((u >> 16) & 1u);
    return (unsigned short)(u >> 16);
}
__device__ __forceinline__ float bf2f(unsigned short h) {
    return __uint_as_float(((unsigned)h) << 16);
}

__device__ __forceinline__ void gload16(const unsigned short* g, unsigned short* l) {
    __builtin_amdgcn_global_load_lds((const __attribute__((address_space(1))) unsigned int*)g,
                                     (__attribute__((address_space(3))) unsigned int*)l,
                                     16, 0, 0);
}

__global__ __launch_bounds__(256) void zero32_k(int* __restrict__ p, int n) {
    int i = blockIdx.x * 256 + threadIdx.x;
    if (i < n) p[i] = 0;
}

__global__ __launch_bounds__(256) void bucket_fill_k(const int* __restrict__ src,
                                                     const int* __restrict__ dst,
                                                     int* __restrict__ cnt,
                                                     int* __restrict__ bkt, int E) {
    int e = blockIdx.x * 256 + threadIdx.x;
    if (e >= E) return;
    int t = dst[e];
    int pos = atomicAdd(&cnt[t], 1);
    if (pos < CAP) bkt[(size_t)t * CAP + pos] = src[e];
}

// fp32 -> bf16 hi + bf16 lo (residual), vectorized
__global__ __launch_bounds__(256) void split_k(const float* __restrict__ x,
                                               unsigned short* __restrict__ hi,
                                               unsigned short* __restrict__ lo,
                                               int n4) {
    int i = blockIdx.x * 256 + threadIdx.x;
    int stride = gridDim.x * 256;
    for (; i < n4; i += stride) {
        float4 v = ((const float4*)x)[i];
        ushort4 h, l;
        h.x = f2bf(v.x); l.x = f2bf(v.x - bf2f(h.x));
        h.y = f2bf(v.y); l.y = f2bf(v.y - bf2f(h.y));
        h.z = f2bf(v.z); l.z = f2bf(v.z - bf2f(h.z));
        h.w = f2bf(v.w); l.w = f2bf(v.w - bf2f(h.w));
        ((ushort4*)hi)[i] = h;
        ((ushort4*)lo)[i] = l;
    }
}

// W [K][256] fp32 -> Wt hi/lo [256][K] bf16 (transpose + split; tiny)
__global__ __launch_bounds__(256) void wsplit_k(const float* __restrict__ W,
                                                unsigned short* __restrict__ hi,
                                                unsigned short* __restrict__ lo, int K) {
    int idx = blockIdx.x * 256 + threadIdx.x;
    if (idx >= K * HD) return;
    int n = idx / K, k = idx - n * K;
    float v = W[(size_t)k * HD + n];
    unsigned short h = f2bf(v);
    hi[idx] = h;
    lo[idx] = f2bf(v - bf2f(h));
}

// C[M,256] = A[M,K] @ B[K,256], split-bf16 MFMA (Ah*Bh + Ah*Bl + Al*Bh), fp32 out.
__global__ __launch_bounds__(256, 2) void gemm_mfma_k(
    const unsigned short* __restrict__ Ahi, const unsigned short* __restrict__ Alo,
    const unsigned short* __restrict__ Bhi, const unsigned short* __restrict__ Blo,
    float* __restrict__ C, int M, int K) {
    __shared__ unsigned short smem[4 * 128 * 32];   // Ahi | Alo | Bhi | Blo, 8KB each
    const int tid = threadIdx.x;
    const int lane = tid & 63;
    const int wv = tid >> 6;
    const int Rw = (wv >> 1) * 64;
    const int Cw = (wv & 1) * 64;
    const int bm = blockIdx.y * 128;
    const int bn = blockIdx.x * 128;

    const int sr0 = tid >> 2;
    const int p = tid & 3;
    const int g0 = p ^ ((sr0 >> 1) & 3);            // inverse-swizzled source slot
    const int g1 = p ^ (((sr0 + 64) >> 1) & 3);
    int ar0 = bm + sr0;      if (ar0 >= M) ar0 = M - 1;
    int ar1 = bm + sr0 + 64; if (ar1 >= M) ar1 = M - 1;
    const int bc0 = bn + sr0;
    const int bc1 = bn + sr0 + 64;
    const size_t aoff0 = (size_t)ar0 * K + g0 * 8;
    const size_t aoff1 = (size_t)ar1 * K + g1 * 8;
    const size_t boff0 = (size_t)bc0 * K + g0 * 8;
    const size_t boff1 = (size_t)bc1 * K + g1 * 8;

    unsigned short* sAh = smem;
    unsigned short* sAl = smem + 4096;
    unsigned short* sBh = smem + 8192;
    unsigned short* sBl = smem + 12288;
    const int ldsb = wv * 512;                      // wave-uniform base (ushorts)

    f32x4 acc[4][4];
#pragma unroll
    for (int m = 0; m < 4; m++)
#pragma unroll
        for (int n = 0; n < 4; n++) acc[m][n] = (f32x4){0.f, 0.f, 0.f, 0.f};

    const int r16 = lane & 15, gq = lane >> 4;
    const int rsw = gq ^ ((r16 >> 1) & 3);          // swizzled read slot

    for (int k0 = 0; k0 < K; k0 += 32) {
        __syncthreads();
        gload16(Ahi + aoff0 + k0, sAh + ldsb);
        gload16(Ahi + aoff1 + k0, sAh + 2048 + ldsb);
        gload16(Alo + aoff0 + k0, sAl + ldsb);
        gload16(Alo + aoff1 + k0, sAl + 2048 + ldsb);
        gload16(Bhi + boff0 + k0, sBh + ldsb);
        gload16(Bhi + boff1 + k0, sBh + 2048 + ldsb);
        gload16(Blo + boff0 + k0, sBl + ldsb);
        gload16(Blo + boff1 + k0, sBl + 2048 + ldsb);
        __syncthreads();

        bf16x8 ah[4], al[4], bh[4], bl[4];
#pragma unroll
        for (int m = 0; m < 4; m++) {
            int off = (Rw + m * 16 + r16) * 32 + rsw * 8;
            ah[m] = *(const bf16x8*)(sAh + off);
            al[m] = *(const bf16x8*)(sAl + off);
        }
#pragma unroll
        for (int n = 0; n < 4; n++) {
            int off = (Cw + n * 16 + r16) * 32 + rsw * 8;
            bh[n] = *(const bf16x8*)(sBh + off);
            bl[n] = *(const bf16x8*)(sBl + off);
        }
#pragma unroll
        for (int m = 0; m < 4; m++)
#pragma unroll
            for (int n = 0; n < 4; n++) {
                acc[m][n] = __builtin_amdgcn_mfma_f32_16x16x32_bf16(ah[m], bh[n], acc[m][n], 0, 0, 0);
                acc[m][n] = __builtin_amdgcn_mfma_f32_16x16x32_bf16(ah[m], bl[n], acc[m][n], 0, 0, 0);
                acc[m][n] = __builtin_amdgcn_mfma_f32_16x16x32_bf16(al[m], bh[n], acc[m][n], 0, 0, 0);
            }
    }

#pragma unroll
    for (int m = 0; m < 4; m++) {
        int rbase = bm + Rw + m * 16 + ((lane >> 4) << 2);
#pragma unroll
        for (int n = 0; n < 4; n++) {
            int col = bn + Cw + n * 16 + r16;
            float* cp = C + (size_t)rbase * HD + col;
            f32x4 v = acc[m][n];
#pragma unroll
            for (int r = 0; r < 4; r++)
                if (rbase + r < M) cp[(size_t)r * HD] = v[r];
        }
    }
}

// per (node,head): a_s = dot(h[n,h,:], a_src[h,:]), a_d likewise
__global__ __launch_bounds__(256) void attscore_k(const float* __restrict__ h,
                                                  const float* __restrict__ a_src,
                                                  const float* __restrict__ a_dst,
                                                  float* __restrict__ out_s,
                                                  float* __restrict__ out_d, int n) {
    int idx = blockIdx.x * 256 + threadIdx.x;
    if (idx >= n * NHEAD) return;
    int head = idx & 7;
    const float* hp = h + (size_t)(idx >> 3) * HD + head * 32;
    const float* ap = a_src + head * 32;
    const float* dp = a_dst + head * 32;
    float s = 0.f, d = 0.f;
#pragma unroll
    for (int j = 0; j < 32; j += 4) {
        float4 hv = *(const float4*)(hp + j);
        float4 av = *(const float4*)(ap + j);
        float4 dv = *(const float4*)(dp + j);
        s += hv.x * av.x + hv.y * av.y + hv.z * av.z + hv.w * av.w;
        d += hv.x * dv.x + hv.y * dv.y + hv.z * dv.z + hv.w * dv.w;
    }
    out_s[idx] = s;
    out_d[idx] = d;
}

__device__ __forceinline__ float leaky02(float x) { return x > 0.f ? x : 0.2f * x; }

// one wave per dst node; 4 independent online-softmax chains over incoming
// edges (merged exactly at the end) to break the serial dep chain.
__global__ __launch_bounds__(256) void agg_k(const float* __restrict__ h,
                                             const float* __restrict__ a_s,
                                             const float* __restrict__ a_d,
                                             const int* __restrict__ cnt,
                                             const int* __restrict__ bkt,
                                             const float* __restrict__ bias,
                                             float* __restrict__ out,
                                             unsigned short* __restrict__ ohi,
                                             unsigned short* __restrict__ olo, int n) {
    int wid = (blockIdx.x * 256 + threadIdx.x) >> 6;
    if (wid >= n) return;
    int lane = threadIdx.x & 63;
    int head = lane >> 3;
    const float4* h4 = (const float4*)h;

    float adt = a_d[wid * NHEAD + head];
    int k = cnt[wid]; if (k > CAP) k = CAP;
    const int* bp = bkt + (size_t)wid * CAP;
    int sj = bp[lane];                      // coalesced index preload (garbage beyond k, never used)

    // chain 0 starts with the self loop
    float m0 = leaky02(a_s[wid * NHEAD + head] + adt), den0 = 1.f;
    float4 hv = h4[(size_t)wid * 64 + lane];
    float4 A0 = hv, A1 = {0,0,0,0}, A2 = {0,0,0,0}, A3 = {0,0,0,0};
    float m1 = -3.0e38f, m2 = -3.0e38f, m3 = -3.0e38f;
    float den1 = 0.f, den2 = 0.f, den3 = 0.f;

    int i = 0;
    for (; i + 3 < k; i += 4) {
        int s0 = __shfl(sj, i), s1 = __shfl(sj, i + 1);
        int s2 = __shfl(sj, i + 2), s3 = __shfl(sj, i + 3);
        float e0 = a_s[s0 * NHEAD + head];
        float e1 = a_s[s1 * NHEAD + head];
        float e2 = a_s[s2 * NHEAD + head];
        float e3 = a_s[s3 * NHEAD + head];
        float4 v0 = h4[(size_t)s0 * 64 + lane];
        float4 v1 = h4[(size_t)s1 * 64 + lane];
        float4 v2 = h4[(size_t)s2 * 64 + lane];
        float4 v3 = h4[(size_t)s3 * 64 + lane];
        e0 = leaky02(e0 + adt); e1 = leaky02(e1 + adt);
        e2 = leaky02(e2 + adt); e3 = leaky02(e3 + adt);
        {
            float nm = fmaxf(m0, e0), c = __expf(m0 - nm), pp = __expf(e0 - nm);
            den0 = den0 * c + pp;
            A0.x = A0.x * c + pp * v0.x; A0.y = A0.y * c + pp * v0.y;
            A0.z = A0.z * c + pp * v0.z; A0.w = A0.w * c + pp * v0.w; m0 = nm;
        }
        {
            float nm = fmaxf(m1, e1), c = __expf(m1 - nm), pp = __expf(e1 - nm);
            den1 = den1 * c + pp;
            A1.x = A1.x * c + pp * v1.x; A1.y = A1.y * c + pp * v1.y;
            A1.z = A1.z * c + pp * v1.z; A1.w = A1.w * c + pp * v1.w; m1 = nm;
        }
        {
            float nm = fmaxf(m2, e2), c = __expf(m2 - nm), pp = __expf(e2 - nm);
            den2 = den2 * c + pp;
            A2.x = A2.x * c + pp * v2.x; A2.y = A2.y * c + pp * v2.y;
            A2.z = A2.z * c + pp * v2.z; A2.w = A2.w * c + pp * v2.w; m2 = nm;
        }
        {
            float nm = fmaxf(m3, e3), c = __expf(m3 - nm), pp = __expf(e3 - nm);
            den3 = den3 * c + pp;
            A3.x = A3.x * c + pp * v3.x; A3.y = A3.y * c + pp * v3.y;
            A3.z = A3.z * c + pp * v3.z; A3.w = A3.w * c + pp * v3.w; m3 = nm;
        }
    }
    for (; i < k; i++) {
        int s = __shfl(sj, i);
        float e = leaky02(a_s[s * NHEAD + head] + adt);
        float4 v = h4[(size_t)s * 64 + lane];
        float nm = fmaxf(m0, e), c = __expf(m0 - nm), pp = __expf(e - nm);
        den0 = den0 * c + pp;
        A0.x = A0.x * c + pp * v.x; A0.y = A0.y * c + pp * v.y;
        A0.z = A0.z * c + pp * v.z; A0.w = A0.w * c + pp * v.w; m0 = nm;
    }
    // exact merge of the 4 chains
    float M = fmaxf(fmaxf(m0, m1), fmaxf(m2, m3));
    float c0 = __expf(m0 - M), c1 = __expf(m1 - M), c2 = __expf(m2 - M), c3 = __expf(m3 - M);
    float den = den0 * c0 + den1 * c1 + den2 * c2 + den3 * c3;
    float ax = A0.x * c0 + A1.x * c1 + A2.x * c2 + A3.x * c3;
    float ay = A0.y * c0 + A1.y * c1 + A2.y * c2 + A3.y * c3;
    float az = A0.z * c0 + A1.z * c1 + A2.z * c2 + A3.z * c3;
    float aw = A0.w * c0 + A1.w * c1 + A2.w * c2 + A3.w * c3;

    float inv = 1.f / den;
    float4 bv = *(const float4*)(bias + lane * 4);
    float ox = fmaf(ax, inv, bv.x);
    float oy = fmaf(ay, inv, bv.y);
    float oz = fmaf(az, inv, bv.z);
    float ow = fmaf(aw, inv, bv.w);
    ox = ox > 0.f ? ox : expm1f(ox);
    oy = oy > 0.f ? oy : expm1f(oy);
    oz = oz > 0.f ? oz : expm1f(oz);
    ow = ow > 0.f ? ow : expm1f(ow);
    ((float4*)out)[(size_t)wid * 64 + lane] = make_float4(ox, oy, oz, ow);
    if (ohi) {
        ushort4 h4o, l4o;
        h4o.x = f2bf(ox); l4o.x = f2bf(ox - bf2f(h4o.x));
        h4o.y = f2bf(oy); l4o.y = f2bf(oy - bf2f(h4o.y));
        h4o.z = f2bf(oz); l4o.z = f2bf(oz - bf2f(h4o.z));
        h4o.w = f2bf(ow); l4o.w = f2bf(ow - bf2f(h4o.w));
        ((ushort4*)ohi)[(size_t)wid * 64 + lane] = h4o;
        ((ushort4*)olo)[(size_t)wid * 64 + lane] = l4o;
    }
}

// fused head: fc1 weights staged in LDS; 64 nodes/block (16 per wave);
// vectorized x loads + 8 independent accumulators.
__global__ __launch_bounds__(256) void head_k(const float* __restrict__ cb,
                                              const float* __restrict__ sb,
                                              const float* __restrict__ attc_w,
                                              const float* __restrict__ attc_b,
                                              const float* __restrict__ atts_w,
                                              const float* __restrict__ atts_b,
                                              const float* __restrict__ fc1_w,
                                              const float* __restrict__ fc1_b,
                                              const float* __restrict__ fc2_w,
                                              const float* __restrict__ fc2_b,
                                              float* __restrict__ out, int n) {
    __shared__ float w1s[512 * 32];                 // 64 KB
    const int tid = threadIdx.x;
    for (int j = tid; j < 512 * 32 / 4; j += 256)
        ((float4*)w1s)[j] = ((const float4*)fc1_w)[j];
    __syncthreads();

    const int lane = tid & 63;
    const int wv = tid >> 6;
    const int col = lane & 31, half = lane >> 5;
    const float f2w = fc2_w[col * 2 + half];
    const float f1b = fc1_b[col];
    const float b20 = fc2_b[0], b21 = fc2_b[1];
    const float acb = attc_b[0], asb_ = atts_b[0];
    float4 wc = *(const float4*)(attc_w + lane * 4);
    float4 ws = *(const float4*)(atts_w + lane * 4);
    const float* wp = w1s + (size_t)half * 256 * 32 + col;

    for (int it = 0; it < 16; it++) {
        int nd = blockIdx.x * 64 + wv * 16 + it;
        if (nd >= n) break;
        const float* c = cb + (size_t)nd * HD;
        const float* s = sb + (size_t)nd * HD;
        float4 cv = ((const float4*)c)[lane];
        float4 sv = ((const float4*)s)[lane];
        float pc = cv.x * wc.x + cv.y * wc.y + cv.z * wc.z + cv.w * wc.w;
        float ps = sv.x * ws.x + sv.y * ws.y + sv.z * ws.z + sv.w * ws.w;
#pragma unroll
        for (int o = 32; o; o >>= 1) { pc += __shfl_xor(pc, o); ps += __shfl_xor(ps, o); }
        float csc = 1.f / (1.f + __expf(-(pc + acb)));
        float ssc = 1.f / (1.f + __expf(-(ps + asb_)));
        float mx0 = fmaxf(csc, ssc);
        float e0 = __expf(csc - mx0), e1 = __expf(ssc - mx0);
        float w0 = e0 / (e0 + e1), w1 = e1 / (e0 + e1);

        const float4* xb4 = (const float4*)(half ? s : c);
        float wsc = half ? w1 : w0;
        float a0 = 0.f, a1 = 0.f, a2 = 0.f, a3 = 0.f, a4 = 0.f, a5 = 0.f, a6 = 0.f, a7 = 0.f;
#pragma unroll 4
        for (int kk = 0; kk < 256; kk += 8) {
            float4 x0 = xb4[kk >> 2];
            float4 x1 = xb4[(kk >> 2) + 1];
            a0 = fmaf(x0.x, wp[(kk + 0) * 32], a0);
            a1 = fmaf(x0.y, wp[(kk + 1) * 32], a1);
            a2 = fmaf(x0.z, wp[(kk + 2) * 32], a2);
            a3 = fmaf(x0.w, wp[(kk + 3) * 32], a3);
            a4 = fmaf(x1.x, wp[(kk + 4) * 32], a4);
            a5 = fmaf(x1.y, wp[(kk + 5) * 32], a5);
            a6 = fmaf(x1.z, wp[(kk + 6) * 32], a6);
            a7 = fmaf(x1.w, wp[(kk + 7) * 32], a7);
        }
        float acc = ((a0 + a1) + (a2 + a3)) + ((a4 + a5) + (a6 + a7));
        acc *= wsc;
        float y = acc + __shfl_xor(acc, 32) + f1b;
        y = y > 0.f ? y : expm1f(y);
        float v = y * f2w;
#pragma unroll
        for (int o = 16; o; o >>= 1) v += __shfl_xor(v, o);
        float z0 = __shfl(v, 0) + b20, z1 = __shfl(v, 32) + b21;
        if (lane == 0) {
            float zm = fmaxf(z0, z1);
            float lse = zm + log1pf(__expf(fminf(z0, z1) - zm));
            out[(size_t)nd * 2]     = z0 - lse;
            out[(size_t)nd * 2 + 1] = z1 - lse;
        }
    }
}

extern "C" void kernel_launch(void* const* d_in, const int* in_sizes, int n_in,
                              void* d_out, int out_size, void* d_ws, size_t ws_size,
                              hipStream_t stream) {
    (void)n_in; (void)out_size; (void)ws_size;
    const float* content_x = (const float*)d_in[0];
    const float* social_x  = (const float*)d_in[1];
    const int*   cei = (const int*)d_in[2];
    const int*   sei = (const int*)d_in[3];
    const float* Wc0  = (const float*)d_in[4];
    const float* ac0s = (const float*)d_in[5];
    const float* ac0d = (const float*)d_in[6];
    const float* bc0  = (const float*)d_in[7];
    const float* Wc1  = (const float*)d_in[8];
    const float* ac1s = (const float*)d_in[9];
    const float* ac1d = (const float*)d_in[10];
    const float* bc1  = (const float*)d_in[11];
    const float* Ws0  = (const float*)d_in[12];
    const float* as0s = (const float*)d_in[13];
    const float* as0d = (const float*)d_in[14];
    const float* bs0  = (const float*)d_in[15];
    const float* Ws1  = (const float*)d_in[16];
    const float* as1s = (const float*)d_in[17];
    const float* as1d = (const float*)d_in[18];
    const float* bs1  = (const float*)d_in[19];
    const float* attc_w = (const float*)d_in[20];
    const float* attc_b = (const float*)d_in[21];
    const float* atts_w = (const float*)d_in[22];
    const float* atts_b = (const float*)d_in[23];
    const float* fc1_w  = (const float*)d_in[24];
    const float* fc1_b  = (const float*)d_in[25];
    const float* fc2_w  = (const float*)d_in[26];
    const float* fc2_b  = (const float*)d_in[27];

    const int E  = in_sizes[2] / 2;        // 400000
    const int CD = in_sizes[4] / HD;       // 768
    const int SD = in_sizes[12] / HD;      // 128
    const int n  = in_sizes[0] / CD;       // 50000

    char* p = (char*)d_ws;
    auto carve = [&](size_t bytes) { char* q = p; p += (bytes + 255) & ~(size_t)255; return q; };
    float* hbuf = (float*)carve((size_t)n * HD * 4);
    float* cbuf = (float*)carve((size_t)n * HD * 4);
    float* sbuf = (float*)carve((size_t)n * HD * 4);
    unsigned short* Xhi = (unsigned short*)carve((size_t)n * CD * 2);
    unsigned short* Xlo = (unsigned short*)carve((size_t)n * CD * 2);
    float* asb  = (float*)carve((size_t)n * NHEAD * 4);
    float* adb  = (float*)carve((size_t)n * NHEAD * 4);
    int* cnt_c  = (int*)carve((size_t)n * 4);
    int* cnt_s  = (int*)carve((size_t)n * 4);
    int* bkt_c  = (int*)carve((size_t)n * CAP * 4);
    int* bkt_s  = (int*)carve((size_t)n * CAP * 4);
    unsigned short* Wc0h = (unsigned short*)carve((size_t)CD * HD * 2);
    unsigned short* Wc0l = (unsigned short*)carve((size_t)CD * HD * 2);
    unsigned short* Wc1h = (unsigned short*)carve((size_t)HD * HD * 2);
    unsigned short* Wc1l = (unsigned short*)carve((size_t)HD * HD * 2);
    unsigned short* Ws0h = (unsigned short*)carve((size_t)SD * HD * 2);
    unsigned short* Ws0l = (unsigned short*)carve((size_t)SD * HD * 2);
    unsigned short* Ws1h = (unsigned short*)carve((size_t)HD * HD * 2);
    unsigned short* Ws1l = (unsigned short*)carve((size_t)HD * HD * 2);

    dim3 b256(256);
    zero32_k<<<dim3((n + 255) / 256), b256, 0, stream>>>(cnt_c, n);
    zero32_k<<<dim3((n + 255) / 256), b256, 0, stream>>>(cnt_s, n);
    bucket_fill_k<<<dim3((E + 255) / 256), b256, 0, stream>>>(cei, cei + E, cnt_c, bkt_c, E);
    bucket_fill_k<<<dim3((E + 255) / 256), b256, 0, stream>>>(sei, sei + E, cnt_s, bkt_s, E);

    // weight transpose+split (tiny)
    wsplit_k<<<dim3((CD * HD + 255) / 256), b256, 0, stream>>>(Wc0, Wc0h, Wc0l, CD);
    wsplit_k<<<dim3((HD * HD + 255) / 256), b256, 0, stream>>>(Wc1, Wc1h, Wc1l, HD);
    wsplit_k<<<dim3((SD * HD + 255) / 256), b256, 0, stream>>>(Ws0, Ws0h, Ws0l, SD);
    wsplit_k<<<dim3((HD * HD + 255) / 256), b256, 0, stream>>>(Ws1, Ws1h, Ws1l, HD);

    dim3 gg(2, (n + 127) / 128);
    dim3 nb8((n * NHEAD + 255) / 256);
    dim3 nwave((n + 3) / 4);

    // content layer 0
    split_k<<<dim3(2048), b256, 0, stream>>>(content_x, Xhi, Xlo, n * CD / 4);
    gemm_mfma_k<<<gg, b256, 0, stream>>>(Xhi, Xlo, Wc0h, Wc0l, hbuf, n, CD);
    attscore_k<<<nb8, b256, 0, stream>>>(hbuf, ac0s, ac0d, asb, adb, n);
    agg_k<<<nwave, b256, 0, stream>>>(hbuf, asb, adb, cnt_c, bkt_c, bc0, cbuf, Xhi, Xlo, n);
    // content layer 1
    gemm_mfma_k<<<gg, b256, 0, stream>>>(Xhi, Xlo, Wc1h, Wc1l, hbuf, n, HD);
    attscore_k<<<nb8, b256, 0, stream>>>(hbuf, ac1s, ac1d, asb, adb, n);
    agg_k<<<nwave, b256, 0, stream>>>(hbuf, asb, adb, cnt_c, bkt_c, bc1, cbuf,
                                      (unsigned short*)nullptr, (unsigned short*)nullptr, n);
    // social layer 0
    split_k<<<dim3(2048), b256, 0, stream>>>(social_x, Xhi, Xlo, n * SD / 4);
    gemm_mfma_k<<<gg, b256, 0, stream>>>(Xhi, Xlo, Ws0h, Ws0l, hbuf, n, SD);
    attscore_k<<<nb8, b256, 0, stream>>>(hbuf, as0s, as0d, asb, adb, n);
    agg_k<<<nwave, b256, 0, stream>>>(hbuf, asb, adb, cnt_s, bkt_s, bs0, sbuf, Xhi, Xlo, n);
    // social layer 1
    gemm_mfma_k<<<gg, b256, 0, stream>>>(Xhi, Xlo, Ws1h, Ws1l, hbuf, n, HD);
    attscore_k<<<nb8, b256, 0, stream>>>(hbuf, as1s, as1d, asb, adb, n);
    agg_k<<<nwave, b256, 0, stream>>>(hbuf, asb, adb, cnt_s, bkt_s, bs1, sbuf,
                                      (unsigned short*)nullptr, (unsigned short*)nullptr, n);

    head_k<<<dim3((n + 63) / 64), b256, 0, stream>>>(cbuf, sbuf, attc_w, attc_b, atts_w, atts_b,
                                                     fc1_w, fc1_b, fc2_w, fc2_b, (float*)d_out, n);
}